// Round 7
// baseline (1514.077 us; speedup 1.0000x reference)
//
#include <hip/hip_runtime.h>
#include <math.h>

#define INF __builtin_inff()
#define SENT 0x7FA00000u
#define IMAX 0x7fffffff

typedef __attribute__((ext_vector_type(8))) short bhalf8;
typedef __attribute__((ext_vector_type(4))) float f32x4;

// ---------------- workspace layout (float offsets) ----------------
// xg      : 0        (1024 x 2048)   plain GEMM output (release-flagged)
// h_seq   : 2097152  (257 x 4 x 512) sentinel data-as-flag
// qbuf    : 2623488  (1024 x 128)  fp32 normalized q
// invn    : 2754560  (100000)
// mem_pre : 2854560  (1024 x 128)
// mem_cmb : 2985632  (1024 x 128)  [0..32] alias: flags (xg 0-15, q 16-31, kc 32)
// pvals   : 3116704  (32 x 1024 x 6)
// pidx    : 3313312  (32 x 1024 x 6) int
// qbf     : 3509920  (1024 x 64 uint)
// kbf     : 3575456  (100000 x 64 uint)

__device__ __forceinline__ void ins3b(float& v0, int& i0, float& v1, int& i1,
                                      float& v2, int& i2, float nv, int ni) {
  bool b0 = (nv > v0) || (nv == v0 && ni < i0);
  bool b1 = (nv > v1) || (nv == v1 && ni < i1);
  bool b2 = (nv > v2) || (nv == v2 && ni < i2);
  v2 = b1 ? v1 : (b2 ? nv : v2);
  i2 = b1 ? i1 : (b2 ? ni : i2);
  v1 = b0 ? v0 : (b1 ? nv : v1);
  i1 = b0 ? i0 : (b1 ? ni : i1);
  v0 = b0 ? nv : v0;
  i0 = b0 ? ni : i0;
}

__device__ __forceinline__ unsigned short f2bf(float x) {  // RNE
  unsigned u = __float_as_uint(x);
  return (unsigned short)((u + 0x7FFFu + ((u >> 16) & 1u)) >> 16);
}

__device__ __forceinline__ float pollf(const float* p) {
  float v;
  do { v = __hip_atomic_load(p, __ATOMIC_RELAXED, __HIP_MEMORY_SCOPE_AGENT); }
  while (__float_as_uint(v) == SENT);
  return v;
}

// h_seq: t=0 slab -> 0, rest sentinel. flags -> 0.
__global__ void init_k(float* __restrict__ h_seq, unsigned* __restrict__ flags) {
  int t = blockIdx.x * 256 + threadIdx.x;   // grid 2056 x 256
  if (t < 526336) h_seq[t] = (t < 2048) ? 0.f : __uint_as_float(SENT);
  if (t < 33) flags[t] = 0u;
}

// ---------------- generic tiled GEMM: C(MxN) = A(MxK) @ B(NxK)^T + bias ----
// AMODE 0 plain. AMODE 2: concat [h | A2(1024x128)], K=640, h via h_seq map.
template<int AMODE>
__global__ __launch_bounds__(256) void gemm_k(
    const float* __restrict__ A, const float* __restrict__ A2,
    const float* __restrict__ Bw, const float* __restrict__ b1,
    const float* __restrict__ b2, float* __restrict__ C,
    int M, int N, int K) {
  __shared__ float4 As4[64][16];
  __shared__ float4 Bs4[64][16];
  const int t = threadIdx.x;
  const int tx = t & 15, ty = t >> 4;
  const int brow = blockIdx.x * 64, bcol = blockIdx.y * 64;
  const int srow = t >> 2, scb = t & 3;
  float acc[4][4] = {};
  for (int kt = 0; kt < K; kt += 64) {
#pragma unroll
    for (int u = 0; u < 4; ++u) {
      int c = scb + 4 * u;
      int gk = kt + c * 4;
      int gr = brow + srow;
      const float* ap;
      if (AMODE == 0) {
        ap = A + (size_t)gr * K + gk;
      } else {
        int b = gr >> 8, s = gr & 255;
        const float* hrow = A + ((size_t)(s + 1) * 4 + b) * 512;
        ap = (gk < 512) ? (hrow + gk) : (A2 + (size_t)gr * 128 + (gk - 512));
      }
      As4[srow][c ^ (srow & 15)] = *(const float4*)ap;
      Bs4[srow][c ^ (srow & 15)] = *(const float4*)(Bw + (size_t)(bcol + srow) * K + gk);
    }
    __syncthreads();
#pragma unroll
    for (int d4 = 0; d4 < 16; ++d4) {
      float4 av[4], bv[4];
#pragma unroll
      for (int i = 0; i < 4; ++i) av[i] = As4[ty * 4 + i][d4 ^ ((ty * 4 + i) & 15)];
#pragma unroll
      for (int j = 0; j < 4; ++j) bv[j] = Bs4[tx * 4 + j][d4 ^ ((tx * 4 + j) & 15)];
#pragma unroll
      for (int i = 0; i < 4; ++i)
#pragma unroll
        for (int j = 0; j < 4; ++j)
          acc[i][j] += av[i].x * bv[j].x + av[i].y * bv[j].y +
                       av[i].z * bv[j].z + av[i].w * bv[j].w;
    }
    __syncthreads();
  }
#pragma unroll
  for (int i = 0; i < 4; ++i) {
    int r = brow + ty * 4 + i;
#pragma unroll
    for (int j = 0; j < 4; ++j) {
      int n = bcol + tx * 4 + j;
      float bias = b1[n];
      if (b2) bias += b2[n];
      C[(size_t)r * N + n] = acc[i][j] + bias;
    }
  }
}

// stage one 64x128-bf16 tile: LINEAR LDS dest (global_load_lds), source
// pre-swizzled so readers XOR-deswizzle. w in 0..3.
__device__ __forceinline__ void stage_tile(unsigned short* dst,
                                           const unsigned* src,
                                           int baserow, int maxrow,
                                           int w, int l) {
#pragma unroll
  for (int u = 0; u < 4; ++u) {
    int s = u * 256 + w * 64 + l;
    int row = s >> 4, cc = s & 15;
    int gr = baserow + row; gr = gr > maxrow ? maxrow : gr;
    const unsigned* sp = src + (size_t)gr * 64 + ((cc ^ (row & 7)) << 2);
    __builtin_amdgcn_global_load_lds(
        (const __attribute__((address_space(1))) unsigned*)sp,
        (__attribute__((address_space(3))) unsigned*)(dst + (size_t)(u * 256 + w * 64) * 8),
        16, 0, 0);
  }
}

// ---------------- mega-fused front ----------------
// bids: 0-63 LSTM | 64-575 xg GEMM | 576-966 keyconv | 967-982 q-producer |
// 983-1494 sims (16 qtiles x 32 chunks). Dataflow via sentinel/flag polls;
// every poller's producers are earlier in dispatch order and poll-free or
// guaranteed-resident (LSTM = first 64 blocks) -> deadlock-free.
__global__ __launch_bounds__(512, 2) void fused_front(
    const float* __restrict__ x, const float* __restrict__ W_ih,
    const float* __restrict__ b_ih, const float* __restrict__ b_hh,
    const float* __restrict__ W_hh, const float* __restrict__ keys,
    const float* __restrict__ Wq, const float* __restrict__ bq,
    float* __restrict__ xg, float* __restrict__ h_seq,
    float* __restrict__ invn, unsigned* __restrict__ kbf,
    float* __restrict__ qbuf, unsigned* __restrict__ qbf,
    float* __restrict__ pvals, int* __restrict__ pidx,
    unsigned* __restrict__ flags) {
  __shared__ alignas(16) unsigned char smem[49152];
  const int bid = blockIdx.x;
  const int t = threadIdx.x;
  unsigned* xgflag = flags;          // [16]
  unsigned* qflag  = flags + 16;     // [16]
  unsigned* kcflag = flags + 32;     // [1]

  if (bid < 64) {
    // ---------------- LSTM (identical to R6) ----------------
    const int batch = bid >> 4;
    const int ub = bid & 15;
    const int uu = t >> 4;
    const int li = t & 15;
    const int unit = ub * 32 + uu;
    float* h_lds = (float*)smem;     // [2][576]

    float w[4][32];
#pragma unroll
    for (int g = 0; g < 4; ++g) {
      const float* wr = W_hh + (size_t)(g * 512 + unit) * 512 + li * 32;
#pragma unroll
      for (int j = 0; j < 32; j += 4) {
        float4 v = *(const float4*)(wr + j);
        w[g][j] = v.x; w[g][j + 1] = v.y; w[g][j + 2] = v.z; w[g][j + 3] = v.w;
      }
    }
    float c = 0.f;
    {
      const unsigned* f0 = xgflag + batch * 4;
      while (__hip_atomic_load(f0, __ATOMIC_RELAXED, __HIP_MEMORY_SCOPE_AGENT) < 32u) {}
      (void)__hip_atomic_load(f0, __ATOMIC_ACQUIRE, __HIP_MEMORY_SCOPE_AGENT);
    }
    float xcur[4], xnxt[4];
    {
      const float* xq = xg + (size_t)(batch * 256) * 2048 + unit;
#pragma unroll
      for (int g = 0; g < 4; ++g) xcur[g] = xq[g * 512];
#pragma unroll
      for (int g = 0; g < 4; ++g) xnxt[g] = xq[2048 + g * 512];
    }

    for (int step = 0; step < 256; ++step) {
      {
        float hv = pollf(h_seq + ((size_t)step * 4 + batch) * 512 + t);
        h_lds[(step & 1) * 576 + (t >> 5) * 36 + (t & 31)] = hv;
      }
      __syncthreads();
      const float* hb = h_lds + (step & 1) * 576 + li * 36;
      float a0 = 0.f, a1 = 0.f, a2 = 0.f, a3 = 0.f;
#pragma unroll
      for (int j = 0; j < 32; j += 4) {
        float4 hv = *(const float4*)(hb + j);
        a0 += w[0][j] * hv.x + w[0][j + 1] * hv.y + w[0][j + 2] * hv.z + w[0][j + 3] * hv.w;
        a1 += w[1][j] * hv.x + w[1][j + 1] * hv.y + w[1][j + 2] * hv.z + w[1][j + 3] * hv.w;
        a2 += w[2][j] * hv.x + w[2][j + 1] * hv.y + w[2][j + 2] * hv.z + w[2][j + 3] * hv.w;
        a3 += w[3][j] * hv.x + w[3][j + 1] * hv.y + w[3][j + 2] * hv.z + w[3][j + 3] * hv.w;
      }
#pragma unroll
      for (int m = 1; m < 16; m <<= 1) {
        a0 += __shfl_xor(a0, m, 64); a1 += __shfl_xor(a1, m, 64);
        a2 += __shfl_xor(a2, m, 64); a3 += __shfl_xor(a3, m, 64);
      }
      a0 += xcur[0]; a1 += xcur[1]; a2 += xcur[2]; a3 += xcur[3];
      float i_ = 1.f / (1.f + expf(-a0));
      float f_ = 1.f / (1.f + expf(-a1));
      float g_ = tanhf(a2);
      float o_ = 1.f / (1.f + expf(-a3));
      c = f_ * c + i_ * g_;
      float h = o_ * tanhf(c);
      if (li == 0)
        __hip_atomic_store(h_seq + ((size_t)(step + 1) * 4 + batch) * 512 + unit,
                           h, __ATOMIC_RELAXED, __HIP_MEMORY_SCOPE_AGENT);
#pragma unroll
      for (int g = 0; g < 4; ++g) xcur[g] = xnxt[g];
      if (step + 2 < 256) {
        if (((step + 2) & 63) == 0) {
          const unsigned* fq = xgflag + batch * 4 + ((step + 2) >> 6);
          while (__hip_atomic_load(fq, __ATOMIC_RELAXED, __HIP_MEMORY_SCOPE_AGENT) < 32u) {}
          (void)__hip_atomic_load(fq, __ATOMIC_ACQUIRE, __HIP_MEMORY_SCOPE_AGENT);
        }
        const float* xq = xg + (size_t)(batch * 256 + step + 2) * 2048 + unit;
#pragma unroll
        for (int g = 0; g < 4; ++g) xnxt[g] = xq[g * 512];
      }
    }
  } else if (bid < 576) {
    // ---------------- xg GEMM ----------------
    const int g = bid - 64;
    const int q = g >> 7;
    const int b = (g >> 5) & 3;
    const int col = g & 31;
    const int brow = (b * 4 + q) * 64, bcol = col * 64;
    float4* As4 = (float4*)smem;
    float4* Bs4 = (float4*)(smem + 16384);
    const int tx = t & 15, ty = (t >> 4) & 15;
    const int srow = (t & 255) >> 2, scb = t & 3;
    float acc[4][4] = {};
    for (int kt = 0; kt < 256; kt += 64) {
      if (t < 256) {
#pragma unroll
        for (int u = 0; u < 4; ++u) {
          int cc = scb + 4 * u;
          int gk = kt + cc * 4;
          As4[srow * 16 + (cc ^ (srow & 15))] =
              *(const float4*)(x + (size_t)(brow + srow) * 256 + gk);
          Bs4[srow * 16 + (cc ^ (srow & 15))] =
              *(const float4*)(W_ih + (size_t)(bcol + srow) * 256 + gk);
        }
      }
      __syncthreads();
      if (t < 256) {
#pragma unroll
        for (int d4 = 0; d4 < 16; ++d4) {
          float4 av[4], bv[4];
#pragma unroll
          for (int i = 0; i < 4; ++i)
            av[i] = As4[(ty * 4 + i) * 16 + (d4 ^ ((ty * 4 + i) & 15))];
#pragma unroll
          for (int j = 0; j < 4; ++j)
            bv[j] = Bs4[(tx * 4 + j) * 16 + (d4 ^ ((tx * 4 + j) & 15))];
#pragma unroll
          for (int i = 0; i < 4; ++i)
#pragma unroll
            for (int j = 0; j < 4; ++j)
              acc[i][j] += av[i].x * bv[j].x + av[i].y * bv[j].y +
                           av[i].z * bv[j].z + av[i].w * bv[j].w;
        }
      }
      __syncthreads();
    }
    if (t < 256) {
#pragma unroll
      for (int i = 0; i < 4; ++i) {
        int r = brow + ty * 4 + i;
#pragma unroll
        for (int j = 0; j < 4; ++j) {
          int n = bcol + tx * 4 + j;
          xg[(size_t)r * 2048 + n] = acc[i][j] + b_ih[n] + b_hh[n];
        }
      }
    }
    __syncthreads();
    if (t == 0)
      __hip_atomic_fetch_add(xgflag + b * 4 + q, 1u, __ATOMIC_RELEASE,
                             __HIP_MEMORY_SCOPE_AGENT);
  } else if (bid < 967) {
    // ---------------- key conversion ----------------
    const int rb = (bid - 576) * 256;
    const int wv = t >> 6, lane = t & 63;
    for (int p = 0; p < 32; ++p) {
      int r = rb + p * 8 + wv;
      if (r < 100000) {
        float2 v = *(const float2*)(keys + (size_t)r * 128 + lane * 2);
        float ss = v.x * v.x + v.y * v.y;
#pragma unroll
        for (int m = 1; m < 64; m <<= 1) ss += __shfl_xor(ss, m, 64);
        float inv = 1.f / fmaxf(sqrtf(ss), 1e-12f);
        if (lane == 0) invn[r] = inv;
        kbf[(size_t)r * 64 + lane] =
            (unsigned)f2bf(v.x * inv) | ((unsigned)f2bf(v.y * inv) << 16);
      }
    }
    __syncthreads();
    if (t == 0)
      __hip_atomic_fetch_add(kcflag, 1u, __ATOMIC_RELEASE,
                             __HIP_MEMORY_SCOPE_AGENT);
  } else if (bid < 983) {
    // ---------------- q-producer: q = l2norm(h @ Wq^T + bq), tile of 64 ----
    const int qt = bid - 967;
    const int b = qt >> 2;
    const int s0 = (qt & 3) * 64;
    float4* A4 = (float4*)smem;            // [64][16]
    float4* B4 = (float4*)(smem + 16384);  // [128][16]
    const int tx = t & 15, ty = (t >> 4) & 15;
    float acc[4][8] = {};
    for (int kt = 0; kt < 512; kt += 64) {
      if (t < 256) {
#pragma unroll
        for (int u = 0; u < 4; ++u) {
          int p = t + 256 * u;
          int row = p >> 4, c4 = p & 15;
          const float* hp = h_seq + ((size_t)(s0 + row + 1) * 4 + b) * 512 + kt + c4 * 4;
          float4 v;
          v.x = pollf(hp + 0); v.y = pollf(hp + 1);
          v.z = pollf(hp + 2); v.w = pollf(hp + 3);
          A4[row * 16 + (c4 ^ (row & 15))] = v;
        }
#pragma unroll
        for (int u = 0; u < 8; ++u) {
          int p = t + 256 * u;
          int row = p >> 4, c4 = p & 15;
          B4[row * 16 + (c4 ^ (row & 15))] =
              *(const float4*)(Wq + (size_t)row * 512 + kt + c4 * 4);
        }
      }
      __syncthreads();
      if (t < 256) {
#pragma unroll
        for (int d4 = 0; d4 < 16; ++d4) {
          float4 av[4], bv[8];
#pragma unroll
          for (int i = 0; i < 4; ++i)
            av[i] = A4[(ty * 4 + i) * 16 + (d4 ^ ((ty * 4 + i) & 15))];
#pragma unroll
          for (int j = 0; j < 8; ++j)
            bv[j] = B4[(tx * 8 + j) * 16 + (d4 ^ ((tx * 8 + j) & 15))];
#pragma unroll
          for (int i = 0; i < 4; ++i)
#pragma unroll
            for (int j = 0; j < 8; ++j)
              acc[i][j] += av[i].x * bv[j].x + av[i].y * bv[j].y +
                           av[i].z * bv[j].z + av[i].w * bv[j].w;
        }
      }
      __syncthreads();
    }
    float* part = (float*)smem;            // [64][16]
    float* invq = (float*)(smem + 4096);   // [64]
    if (t < 256) {
#pragma unroll
      for (int i = 0; i < 4; ++i) {
        float ss = 0.f;
#pragma unroll
        for (int j = 0; j < 8; ++j) {
          acc[i][j] += bq[tx * 8 + j];
          ss += acc[i][j] * acc[i][j];
        }
        part[(ty * 4 + i) * 16 + tx] = ss;
      }
    }
    __syncthreads();
    if (t < 64) {
      float ss = 0.f;
#pragma unroll
      for (int x2 = 0; x2 < 16; ++x2) ss += part[t * 16 + x2];
      invq[t] = 1.f / fmaxf(sqrtf(ss), 1e-12f);
    }
    __syncthreads();
    if (t < 256) {
#pragma unroll
      for (int i = 0; i < 4; ++i) {
        int r = qt * 64 + ty * 4 + i;
        float inv = invq[ty * 4 + i];
        float o[8];
#pragma unroll
        for (int j = 0; j < 8; ++j) o[j] = acc[i][j] * inv;
        *(float4*)(qbuf + (size_t)r * 128 + tx * 8) =
            make_float4(o[0], o[1], o[2], o[3]);
        *(float4*)(qbuf + (size_t)r * 128 + tx * 8 + 4) =
            make_float4(o[4], o[5], o[6], o[7]);
#pragma unroll
        for (int j2 = 0; j2 < 4; ++j2)
          qbf[(size_t)r * 64 + tx * 4 + j2] =
              (unsigned)f2bf(o[j2 * 2]) | ((unsigned)f2bf(o[j2 * 2 + 1]) << 16);
      }
    }
    __syncthreads();
    if (t == 0)
      __hip_atomic_fetch_add(qflag + qt, 1u, __ATOMIC_RELEASE,
                             __HIP_MEMORY_SCOPE_AGENT);
  } else {
    // ---------------- sims: bf16 MFMA + per-chunk top-6 candidates --------
    const int sidx = bid - 983;
    const int qt = sidx >> 5, ch = sidx & 31;
    const int kbeg = ch * 3125, klim = kbeg + 3125;   // 49 steps of 64
    const int l = t & 63, w4 = t >> 6;                // w4 0..7; 0..3 active
    unsigned short* ks0 = (unsigned short*)smem;
    unsigned short* ks1 = (unsigned short*)(smem + 16384);

    if (t == 0) {
      while (__hip_atomic_load(kcflag, __ATOMIC_RELAXED, __HIP_MEMORY_SCOPE_AGENT) < 391u)
        __builtin_amdgcn_s_sleep(8);
      while (__hip_atomic_load(qflag + qt, __ATOMIC_RELAXED, __HIP_MEMORY_SCOPE_AGENT) < 1u)
        __builtin_amdgcn_s_sleep(8);
      (void)__hip_atomic_load(qflag + qt, __ATOMIC_ACQUIRE, __HIP_MEMORY_SCOPE_AGENT);
    }
    __syncthreads();

    if (w4 < 4) stage_tile(ks1, qbf, qt * 64, 1023, w4, l);
    __syncthreads();
    bhalf8 afrag[4];
    if (w4 < 4) {
      int row = w4 * 16 + (l & 15);
#pragma unroll
      for (int db = 0; db < 4; ++db) {
        int cslot = db * 4 + (l >> 4);
        afrag[db] = *(const bhalf8*)&ks1[(size_t)(row * 16 + (cslot ^ (row & 7))) * 8];
      }
      stage_tile(ks0, kbf, kbeg, klim - 1, w4, l);
    }
    __syncthreads();

    float tv0[4], tv1[4], tv2[4]; int ti0[4], ti1[4], ti2[4];
#pragma unroll
    for (int r = 0; r < 4; ++r) {
      tv0[r] = tv1[r] = tv2[r] = -INF;
      ti0[r] = ti1[r] = ti2[r] = IMAX;
    }

    for (int s = 0; s < 49; ++s) {
      if (w4 < 4) {
        unsigned short* cur = (s & 1) ? ks1 : ks0;
        unsigned short* nxt = (s & 1) ? ks0 : ks1;
        if (s < 48) stage_tile(nxt, kbf, kbeg + (s + 1) * 64, klim - 1, w4, l);
        int k0 = kbeg + s * 64;
        f32x4 ac0 = {0,0,0,0}, ac1 = {0,0,0,0}, ac2 = {0,0,0,0}, ac3 = {0,0,0,0};
        const int r0 = l & 15;
#pragma unroll
        for (int db = 0; db < 4; ++db) {
          int swz = (db * 4 + (l >> 4)) ^ (r0 & 7);
          bhalf8 b0 = *(const bhalf8*)&cur[(size_t)((r0     ) * 16 + swz) * 8];
          bhalf8 b1 = *(const bhalf8*)&cur[(size_t)((r0 + 16) * 16 + swz) * 8];
          bhalf8 b2 = *(const bhalf8*)&cur[(size_t)((r0 + 32) * 16 + swz) * 8];
          bhalf8 b3 = *(const bhalf8*)&cur[(size_t)((r0 + 48) * 16 + swz) * 8];
          ac0 = __builtin_amdgcn_mfma_f32_16x16x32_bf16(afrag[db], b0, ac0, 0, 0, 0);
          ac1 = __builtin_amdgcn_mfma_f32_16x16x32_bf16(afrag[db], b1, ac1, 0, 0, 0);
          ac2 = __builtin_amdgcn_mfma_f32_16x16x32_bf16(afrag[db], b2, ac2, 0, 0, 0);
          ac3 = __builtin_amdgcn_mfma_f32_16x16x32_bf16(afrag[db], b3, ac3, 0, 0, 0);
        }
#pragma unroll
        for (int nt = 0; nt < 4; ++nt) {
          f32x4 a = (nt == 0) ? ac0 : (nt == 1) ? ac1 : (nt == 2) ? ac2 : ac3;
          int gk = k0 + nt * 16 + (l & 15);
          bool ok = gk < klim;
#pragma unroll
          for (int r = 0; r < 4; ++r) {
            float v = ok ? a[r] : -INF;
            ins3b(tv0[r], ti0[r], tv1[r], ti1[r], tv2[r], ti2[r], v, gk);
          }
        }
      }
      __syncthreads();
    }

    if (w4 < 4) {
#pragma unroll
      for (int r = 0; r < 4; ++r) {
        float c0 = tv0[r], c1 = tv1[r], c2 = tv2[r];
        int j0 = ti0[r], j1 = ti1[r], j2 = ti2[r];
        int qrow = qt * 64 + w4 * 16 + (l >> 4) * 4 + r;
        size_t ob = ((size_t)ch * 1024 + qrow) * 6;
#pragma unroll
        for (int e = 0; e < 6; ++e) {
          float mv = c0; int mi = j0;
#pragma unroll
          for (int m = 1; m < 16; m <<= 1) {
            float o = __shfl_xor(mv, m, 64); int oi = __shfl_xor(mi, m, 64);
            bool tk = (o > mv) || (o == mv && oi < mi);
            mv = tk ? o : mv; mi = tk ? oi : mi;
          }
          if (mi == j0) { c0 = c1; j0 = j1; c1 = c2; j1 = j2; c2 = -INF; j2 = IMAX; }
          if ((l & 15) == 0) { pvals[ob + e] = mv; pidx[ob + e] = mi; }
        }
      }
    }
  }
}

// ---------------- merge chunks + fp32 rescore + attention ------------------
__global__ __launch_bounds__(256) void merge_rescore_k(
    const float* __restrict__ pvals, const int* __restrict__ pidx,
    const float* __restrict__ qf, const float* __restrict__ keys,
    const float* __restrict__ invn, const float* __restrict__ mvals,
    const float* __restrict__ Wa, const float* __restrict__ ba,
    float* __restrict__ mem_pre) {
  int wv = threadIdx.x >> 6, l = threadIdx.x & 63;
  int qr = blockIdx.x * 4 + wv;
  float h0 = -INF, h1 = -INF, h2 = -INF;
  int g0 = IMAX, g1 = IMAX, g2 = IMAX;
#pragma unroll
  for (int e = 0; e < 3; ++e) {
    int c = l * 3 + e;
    size_t base = ((size_t)(c / 6) * 1024 + qr) * 6 + (c % 6);
    ins3b(h0, g0, h1, g1, h2, g2, pvals[base], pidx[base]);
  }
  float sc[8]; int si[8];
#pragma unroll
  for (int e = 0; e < 8; ++e) {
    float mv = h0; int mi = g0;
#pragma unroll
    for (int m = 1; m < 64; m <<= 1) {
      float o = __shfl_xor(mv, m, 64); int oi = __shfl_xor(mi, m, 64);
      bool tk = (o > mv) || (o == mv && oi < mi);
      mv = tk ? o : mv; mi = tk ? oi : mi;
    }
    sc[e] = mv; si[e] = mi;
    if (mi == g0) { h0 = h1; g0 = g1; h1 = h2; g1 = g2; h2 = -INF; g2 = IMAX; }
  }
  int d = l * 2;
  float q0 = qf[(size_t)qr * 128 + d], q1 = qf[(size_t)qr * 128 + d + 1];
  float ex[8];
#pragma unroll
  for (int e = 0; e < 8; ++e) {
    int k = si[e];
    float p = q0 * keys[(size_t)k * 128 + d] + q1 * keys[(size_t)k * 128 + d + 1];
#pragma unroll
    for (int m = 1; m < 64; m <<= 1) p += __shfl_xor(p, m, 64);
    ex[e] = p * invn[k];
  }
  float v0 = -INF, v1 = -INF, v2 = -INF;
  int i0 = IMAX, i1 = IMAX, i2 = IMAX;
#pragma unroll
  for (int e = 0; e < 8; ++e) ins3b(v0, i0, v1, i1, v2, i2, ex[e], si[e]);
  float r00 = mvals[(size_t)i0 * 128 + d], r01 = mvals[(size_t)i0 * 128 + d + 1];
  float r10 = mvals[(size_t)i1 * 128 + d], r11 = mvals[(size_t)i1 * 128 + d + 1];
  float r20 = mvals[(size_t)i2 * 128 + d], r21 = mvals[(size_t)i2 * 128 + d + 1];
  float wa0 = Wa[d], wa1 = Wa[d + 1];
  float p0 = wa0 * r00 + wa1 * r01;
  float p1 = wa0 * r10 + wa1 * r11;
  float p2 = wa0 * r20 + wa1 * r21;
#pragma unroll
  for (int m = 1; m < 64; m <<= 1) {
    p0 += __shfl_xor(p0, m, 64);
    p1 += __shfl_xor(p1, m, 64);
    p2 += __shfl_xor(p2, m, 64);
  }
  float bav = ba[0];
  float l0 = p0 + bav, l1 = p1 + bav, l2 = p2 + bav;
  float mx = fmaxf(l0, fmaxf(l1, l2));
  float e0 = expf(l0 - mx), e1 = expf(l1 - mx), e2 = expf(l2 - mx);
  float s = e0 + e1 + e2;
  float a0 = e0 / s, a1 = e1 / s, a2 = e2 / s;
  mem_pre[(size_t)qr * 128 + d]     = a0 * r00 + a1 * r10 + a2 * r20;
  mem_pre[(size_t)qr * 128 + d + 1] = a0 * r01 + a1 * r11 + a2 * r21;
}

// ---------------------------------------------------------------------------
extern "C" void kernel_launch(void* const* d_in, const int* in_sizes, int n_in,
                              void* d_out, int out_size, void* d_ws, size_t ws_size,
                              hipStream_t stream) {
  (void)in_sizes; (void)n_in; (void)out_size; (void)ws_size;
  const float* x    = (const float*)d_in[0];
  const float* W_ih = (const float*)d_in[1];
  const float* W_hh = (const float*)d_in[2];
  const float* b_ih = (const float*)d_in[3];
  const float* b_hh = (const float*)d_in[4];
  const float* Wq   = (const float*)d_in[5];
  const float* bq   = (const float*)d_in[6];
  const float* Wa   = (const float*)d_in[7];
  const float* ba   = (const float*)d_in[8];
  const float* Wc   = (const float*)d_in[9];
  const float* bc   = (const float*)d_in[10];
  const float* Wo   = (const float*)d_in[11];
  const float* bo   = (const float*)d_in[12];
  const float* keys = (const float*)d_in[13];
  const float* vals = (const float*)d_in[14];

  float* ws      = (float*)d_ws;
  float* xg      = ws + 0;
  float* h_seq   = ws + 2097152;
  float* qbuf    = ws + 2623488;
  float* invn    = ws + 2754560;
  float* mem_pre = ws + 2854560;
  float* mem_cmb = ws + 2985632;
  float* pvals   = ws + 3116704;
  int*   pidx    = (int*)(ws + 3313312);
  unsigned* qbf  = (unsigned*)(ws + 3509920);
  unsigned* kbf  = (unsigned*)(ws + 3575456);
  unsigned* flags = (unsigned*)mem_cmb;  // dead until gemm_k<0> overwrites

  init_k<<<2056, 256, 0, stream>>>(h_seq, flags);
  fused_front<<<1495, 512, 0, stream>>>(x, W_ih, b_ih, b_hh, W_hh, keys, Wq, bq,
                                        xg, h_seq, invn, kbf, qbuf, qbf,
                                        pvals, pidx, flags);
  merge_rescore_k<<<256, 256, 0, stream>>>(pvals, pidx, qbuf, keys, invn, vals,
                                           Wa, ba, mem_pre);
  gemm_k<0><<<dim3(16, 2), 256, 0, stream>>>(mem_pre, nullptr, Wc, bc, nullptr,
                                             mem_cmb, 1024, 128, 128);
  gemm_k<2><<<dim3(16, 4), 256, 0, stream>>>(h_seq, mem_cmb, Wo, bo, nullptr,
                                             (float*)d_out, 1024, 256, 640);
}